// Round 1
// baseline (58.453 us; speedup 1.0000x reference)
//
#include <hip/hip_runtime.h>

// Problem constants
#define BB 128
#define SS 512
#define CC 64
#define PP 96
#define NW 6
#define NTOP 4

// ws layout (in floats)
#define WS_WCATT 0                   // [512][128]  (rows s, cols r: r<96 = M1^T, 96..101 = W_query^T, rest 0)
#define WS_M2T   65536               // [104][96]
#define WS_CONST (65536 + 9984)      // [96]
#define WS_QBIAS (65536 + 9984 + 96) // [6]
// total 75622 floats = 302,488 bytes

__global__ __launch_bounds__(128) void prep_kernel(
    const float* __restrict__ W_query, const float* __restrict__ b_query,
    const float* __restrict__ W_x,     const float* __restrict__ b_x,
    const float* __restrict__ W_ret0,  const float* __restrict__ b_ret0,
    const float* __restrict__ W_ret1,  const float* __restrict__ b_ret1,
    const float* __restrict__ W_ret2,  const float* __restrict__ b_ret2,
    const float* __restrict__ W_pred,  const float* __restrict__ b_pred,
    const float* __restrict__ angles,  const int* __restrict__ wires,
    float* __restrict__ ws)
{
    const int bid = blockIdx.x;
    const int t = threadIdx.x;
    if (bid < 512) {
        // WcatT[s][r] : s = bid, r = t
        const int s = bid;
        float v = 0.f;
        if (t < 96) {
            // M1[r][s] = sum_k W_pred[r][k] * W_x[k][s]
            #pragma unroll 8
            for (int k = 0; k < 96; ++k)
                v += W_pred[t * 192 + k] * W_x[k * 512 + s];
        } else if (t < 102) {
            v = W_query[(t - 96) * 512 + s];
        }
        ws[WS_WCATT + s * 128 + t] = v;
    } else if (bid < 616) {
        const int jg = bid - 512;
        if (t < 96) {
            const float* Wr; int d, j;
            if (jg < 48)      { Wr = W_ret0; d = 48; j = jg; }
            else if (jg < 80) { Wr = W_ret1; d = 32; j = jg - 48; }
            else              { Wr = W_ret2; d = 24; j = jg - 80; }
            float v = 0.f;
            #pragma unroll 8
            for (int k = 0; k < 96; ++k)
                v += W_pred[t * 192 + 96 + k] * Wr[k * d + j];
            ws[WS_M2T + jg * 96 + t] = v;
        }
    } else {
        if (t < 96) {
            float v = b_pred[t];
            for (int k = 0; k < 96; ++k) {
                v += W_pred[t * 192 + k] * b_x[k];
                v += W_pred[t * 192 + 96 + k] * (b_ret0[k] + b_ret1[k] + b_ret2[k]);
            }
            ws[WS_CONST + t] = v;
        } else if (t < 102) {
            const int w = t - 96;
            float v = b_query[w];
            for (int k = 0; k < 18; ++k)
                if (wires[k] == w) v += angles[k];
            ws[WS_QBIAS + w] = v;
        }
    }
}

// Main fused kernel.
// Grid: 256 blocks = (b, c-half). Block: 256 threads.
// Thread (cg = t&7, rg = t>>3) owns rows r = rg*4..rg*4+3 and cols c = cbase + cg*4..+3.
// Rows 0..95 -> output rows; rows 96..101 -> q values; 102..127 -> zero pad.
__global__ __launch_bounds__(256) void main_kernel(
    const float* __restrict__ x_enc,
    const int*   __restrict__ index,
    const float* __restrict__ W_prob,
    const float* __restrict__ b_prob,
    const float* __restrict__ RT,
    const float* __restrict__ gumbel,
    const float* __restrict__ ws,
    float* __restrict__ out)
{
    const float* __restrict__ WcatT = ws + WS_WCATT;
    const float* __restrict__ M2T   = ws + WS_M2T;
    const float* __restrict__ cst96 = ws + WS_CONST;
    const float* __restrict__ qbias = ws + WS_QBIAS;

    const int bid = blockIdx.x;
    const int b = bid >> 1;
    const int cbase = (bid & 1) * 32;
    const int t = threadIdx.x;
    const int cg = t & 7;
    const int rg = t >> 3;

    __shared__ __align__(16) union {
        struct { float xt[64][32]; float wt[64][128]; } p1;   // 40 KB
        struct { float sel[104][32]; float m2[104][96]; } p2; // 52 KB
    } sh;
    __shared__ float xoffs[32];
    __shared__ float qrows[6][32];
    __shared__ int   m_arr[32];

    const float* __restrict__ xb = x_enc + (size_t)b * (SS * CC);
    if (t < 32) xoffs[t] = xb[511 * 64 + cbase + t];

    float acc[4][4] = {};

    // ---------- Phase 1: acc[r][c] = sum_s WcatT[s][r] * (x[s][c] - xoff[c]) ----------
    for (int ch = 0; ch < 8; ++ch) {
        const int s0 = ch * 64;
        __syncthreads();  // protects xoffs (first iter) and prev-chunk reads
        // stage x tile: 64 s-rows x 32 c, as float4
        #pragma unroll
        for (int L = t; L < 64 * 8; L += 256) {  // 512 float4 loads
            const int sl = L >> 3, q = L & 7;
            float4 v = *(const float4*)&xb[(s0 + sl) * 64 + cbase + q * 4];
            v.x -= xoffs[q * 4 + 0];
            v.y -= xoffs[q * 4 + 1];
            v.z -= xoffs[q * 4 + 2];
            v.w -= xoffs[q * 4 + 3];
            *(float4*)&sh.p1.xt[sl][q * 4] = v;
        }
        // stage WcatT chunk: 64 s-rows x 128 r, as float4
        #pragma unroll
        for (int L = t; L < 64 * 32; L += 256) {  // 2048 float4 loads
            const int sl = L >> 5, rq = L & 31;
            float4 v = *(const float4*)&WcatT[(size_t)(s0 + sl) * 128 + rq * 4];
            *(float4*)&sh.p1.wt[sl][rq * 4] = v;
        }
        __syncthreads();
        #pragma unroll 4
        for (int sl = 0; sl < 64; ++sl) {
            float4 xv = *(const float4*)&sh.p1.xt[sl][cg * 4];
            float4 wv = *(const float4*)&sh.p1.wt[sl][rg * 4];
            float xr[4] = { xv.x, xv.y, xv.z, xv.w };
            float wr[4] = { wv.x, wv.y, wv.z, wv.w };
            #pragma unroll
            for (int rr = 0; rr < 4; ++rr)
                #pragma unroll
                for (int k = 0; k < 4; ++k)
                    acc[rr][k] += wr[rr] * xr[k];
        }
    }

    // ---------- Phase 1.5: q -> cos -> logits -> gumbel argmax ----------
    if (rg == 24) {          // rows 96..99 -> wires 0..3
        #pragma unroll
        for (int rr = 0; rr < 4; ++rr)
            #pragma unroll
            for (int k = 0; k < 4; ++k)
                qrows[rr][cg * 4 + k] = acc[rr][k];
    } else if (rg == 25) {   // rows 100..101 -> wires 4,5
        #pragma unroll
        for (int rr = 0; rr < 2; ++rr)
            #pragma unroll
            for (int k = 0; k < 4; ++k)
                qrows[4 + rr][cg * 4 + k] = acc[rr][k];
    }
    __syncthreads();  // (A) phase-1 LDS reads complete; qrows visible

    // stage M2T into LDS (contiguous copy) -- overlaps old p1 region, safe after (A)
    {
        float* m2lin = &sh.p2.m2[0][0];
        for (int L = t; L < 104 * 96; L += 256)
            m2lin[L] = M2T[L];
    }
    if (t < 32) {
        const int c = t;
        float e[6];
        #pragma unroll
        for (int w = 0; w < 6; ++w)
            e[w] = cosf(qrows[w][c] + qbias[w]);
        const int grow = (b * 64 + cbase + c) * 4;
        float best = -1e30f; int bm = 0;
        #pragma unroll
        for (int m = 0; m < 4; ++m) {
            float lg = b_prob[m];
            #pragma unroll
            for (int w = 0; w < 6; ++w)
                lg += W_prob[m * 6 + w] * e[w];
            const float z = (lg + gumbel[grow + m]) * 2.0f;  // /0.5
            if (z > best) { best = z; bm = m; }               // first-max like jnp.argmax
        }
        m_arr[c] = bm;
    }
    __syncthreads();  // (B) m_arr and m2 ready

    // ---------- Phase 2: gather selected RT rows, apply M2 ----------
    {
        const int idxb = index[b];
        for (int L = t; L < 104 * 32; L += 256) {
            const int jg = L >> 5, cl = L & 31;
            const int m = m_arr[cl];
            int i, row;
            if (jg < 48)      { i = 0; row = jg * 2; }
            else if (jg < 80) { i = 1; row = (jg - 48) * 3; }
            else              { i = 2; row = (jg - 80) * 4; }
            const size_t a = (size_t)i * 122880000ull + (size_t)idxb * 24576ull
                           + (size_t)m * 6144ull + (size_t)row * 64ull + cbase + cl;
            sh.p2.sel[jg][cl] = RT[a];
        }
    }
    __syncthreads();  // (C)

    if (rg < 24) {
        #pragma unroll 4
        for (int jg = 0; jg < 104; ++jg) {
            float4 sv = *(const float4*)&sh.p2.sel[jg][cg * 4];
            float4 mv = *(const float4*)&sh.p2.m2[jg][rg * 4];
            float sr[4] = { sv.x, sv.y, sv.z, sv.w };
            float mr[4] = { mv.x, mv.y, mv.z, mv.w };
            #pragma unroll
            for (int rr = 0; rr < 4; ++rr)
                #pragma unroll
                for (int k = 0; k < 4; ++k)
                    acc[rr][k] += mr[rr] * sr[k];
        }
        // ---------- Output: + const + x_offset ----------
        const size_t ob = (size_t)b * (PP * CC) + cbase + cg * 4;
        #pragma unroll
        for (int rr = 0; rr < 4; ++rr) {
            const int p = rg * 4 + rr;
            const float cv = cst96[p];
            float4 o;
            o.x = acc[rr][0] + cv + xoffs[cg * 4 + 0];
            o.y = acc[rr][1] + cv + xoffs[cg * 4 + 1];
            o.z = acc[rr][2] + cv + xoffs[cg * 4 + 2];
            o.w = acc[rr][3] + cv + xoffs[cg * 4 + 3];
            *(float4*)&out[ob + (size_t)p * 64] = o;
        }
    }
}

extern "C" void kernel_launch(void* const* d_in, const int* in_sizes, int n_in,
                              void* d_out, int out_size, void* d_ws, size_t ws_size,
                              hipStream_t stream) {
    (void)in_sizes; (void)n_in; (void)out_size; (void)ws_size;
    const float* x_enc   = (const float*)d_in[0];
    const int*   index   = (const int*)d_in[1];
    const float* W_query = (const float*)d_in[2];
    const float* b_query = (const float*)d_in[3];
    const float* W_x     = (const float*)d_in[4];
    const float* b_x     = (const float*)d_in[5];
    const float* W_prob  = (const float*)d_in[6];
    const float* b_prob  = (const float*)d_in[7];
    const float* W_ret0  = (const float*)d_in[8];
    const float* b_ret0  = (const float*)d_in[9];
    const float* W_ret1  = (const float*)d_in[10];
    const float* b_ret1  = (const float*)d_in[11];
    const float* W_ret2  = (const float*)d_in[12];
    const float* b_ret2  = (const float*)d_in[13];
    const float* W_pred  = (const float*)d_in[14];
    const float* b_pred  = (const float*)d_in[15];
    const float* RT      = (const float*)d_in[16];
    const float* angles  = (const float*)d_in[17];
    const int*   wires   = (const int*)d_in[18];
    const float* gumbel  = (const float*)d_in[19];
    float* out = (float*)d_out;
    float* ws  = (float*)d_ws;

    prep_kernel<<<617, 128, 0, stream>>>(W_query, b_query, W_x, b_x,
                                         W_ret0, b_ret0, W_ret1, b_ret1, W_ret2, b_ret2,
                                         W_pred, b_pred, angles, wires, ws);
    main_kernel<<<256, 256, 0, stream>>>(x_enc, index, W_prob, b_prob, RT, gumbel, ws, out);
}

// Round 2
// 30.081 us; speedup vs baseline: 1.9432x; 1.9432x over previous
//
#include <hip/hip_runtime.h>

// ---------------- types / helpers ----------------
typedef short bf16x8 __attribute__((ext_vector_type(8)));
typedef float f32x4  __attribute__((ext_vector_type(4)));

// ws layout (floats): [0,30720) = Apack (61440 bf16 = 10 chunks * 12288 B)
//                     [30720,30816) = cst96, [30816,30822) = qbias
#define WS_CONST 30720
#define WS_QBIAS 30816

__device__ __forceinline__ short f2bf(float f) {
    unsigned u = __float_as_uint(f);
    unsigned r = (u + 0x7FFFu + ((u >> 16) & 1u)) >> 16;  // RNE
    return (short)r;
}

// ---------------- prep: pack A = [M1 | M2] into MFMA fragment order (bf16) ----------------
// Apack chunk layout (12288 B each, chunks 0..9):
//   [ks 0..1][mt 0..5][lane 0..63][8 bf16]   elem e of lane holds M[mt*16+(lane&15)][k0 + 8*(lane>>4) + e]
// chunks 0..7: M1 (k = s, 0..511); chunks 8..9: M2 (k = 512 + j, j 0..127, zero for j>=104)
__global__ __launch_bounds__(256) void prep_kernel(
    const float* __restrict__ W_query, const float* __restrict__ b_query,
    const float* __restrict__ W_x,     const float* __restrict__ b_x,
    const float* __restrict__ W_ret0,  const float* __restrict__ b_ret0,
    const float* __restrict__ W_ret1,  const float* __restrict__ b_ret1,
    const float* __restrict__ W_ret2,  const float* __restrict__ b_ret2,
    const float* __restrict__ W_pred,  const float* __restrict__ b_pred,
    const float* __restrict__ angles,  const int* __restrict__ wires,
    float* __restrict__ ws)
{
    const int bid = blockIdx.x;
    const int t = threadIdx.x;
    __shared__ float wp[9216];   // W_pred half [96][96]
    __shared__ float wsl[768];   // slice [96][8]
    short* ap = (short*)ws;

    if (bid < 80) {
        const bool isM1 = bid < 64;
        for (int L = t; L < 9216; L += 256) {
            int r = L / 96, k = L - r * 96;
            wp[L] = W_pred[r * 192 + (isM1 ? k : 96 + k)];
        }
        if (isM1) {
            const int s0 = bid * 8;
            for (int L = t; L < 768; L += 256) {
                int k = L >> 3, s = L & 7;
                wsl[L] = W_x[k * 512 + s0 + s];
            }
        } else {
            const int j0 = (bid - 64) * 8;
            for (int L = t; L < 768; L += 256) {
                int k = L >> 3, jj = L & 7;
                int j = j0 + jj;
                float v = 0.f;
                if (j < 104) {
                    const float* Wr; int d, jl;
                    if (j < 48)      { Wr = W_ret0; d = 48; jl = j; }
                    else if (j < 80) { Wr = W_ret1; d = 32; jl = j - 48; }
                    else             { Wr = W_ret2; d = 24; jl = j - 80; }
                    v = Wr[k * d + jl];
                }
                wsl[L] = v;
            }
        }
        __syncthreads();
        #pragma unroll
        for (int i = 0; i < 3; ++i) {
            int idx = t + i * 256;             // 0..767
            int r = idx >> 3, s = idx & 7;
            float acc = 0.f;
            #pragma unroll 8
            for (int k = 0; k < 96; ++k) acc += wp[r * 96 + k] * wsl[k * 8 + s];
            int sg = isM1 ? (bid * 8 + s) : (512 + (bid - 64) * 8 + s);
            int chunk = sg >> 6, ks = (sg >> 5) & 1, s32 = sg & 31;
            int g = s32 >> 3, e = s32 & 7;
            ap[(chunk * 2 + ks) * 3072 + (r >> 4) * 512 + (g * 16 + (r & 15)) * 8 + e] = f2bf(acc);
        }
    } else {
        if (t < 96) {
            float v = b_pred[t];
            for (int k = 0; k < 96; ++k) {
                v += W_pred[t * 192 + k] * b_x[k];
                v += W_pred[t * 192 + 96 + k] * (b_ret0[k] + b_ret1[k] + b_ret2[k]);
            }
            ws[WS_CONST + t] = v;
        } else if (t < 102) {
            int w = t - 96;
            float v = b_query[w];
            for (int k = 0; k < 18; ++k)
                if (wires[k] == w) v += angles[k];
            ws[WS_QBIAS + w] = v;
        }
    }
}

// ---------------- main fused kernel ----------------
// grid 512 = (b 0..127) x (cq 0..3, 16 cols each); 512 threads = 8 waves.
// waves 0..5: one 16x16 output tile each (rows w*16..w*16+15, cols cbase..cbase+15), K = 640.
// waves 6..7: x staging. phase-0 computes fp32 q + gumbel argmax (m_sel per col).
__global__ __launch_bounds__(512) void main_kernel(
    const float* __restrict__ x_enc,
    const int*   __restrict__ index,
    const float* __restrict__ W_query,
    const float* __restrict__ W_prob,
    const float* __restrict__ b_prob,
    const float* __restrict__ RT,
    const float* __restrict__ gumbel,
    const float* __restrict__ ws,
    float* __restrict__ out)
{
    const int bid = blockIdx.x;
    const int b = bid >> 2;
    const int cbase = (bid & 3) * 16;
    const int t = threadIdx.x;

    __shared__ __align__(16) unsigned char uni[13056];   // Abuf(12288 B) U qp(3264 f32)
    __shared__ __align__(16) short xbuf[16 * 72];        // [c 16][k 64 pad 72] bf16
    __shared__ __align__(16) short selbuf[16 * 136];     // [c 16][j 128 pad 136] bf16
    __shared__ float xoffs[16];
    __shared__ float qfin[104];                          // [w 6][17]
    __shared__ int   m_sel[16];

    const float* __restrict__ xb = x_enc + (size_t)b * 32768;
    if (t < 16) xoffs[t] = xb[511 * 64 + cbase + t];
    __syncthreads();

    // ---- phase 0: fp32 q = W_query @ xnorm (exact-precision path for argmax) ----
    {
        int c = t & 15, sg = t >> 4;                     // sg 0..31, 16 s each
        float xo = xoffs[c];
        float a0 = 0, a1 = 0, a2 = 0, a3 = 0, a4 = 0, a5 = 0;
        const float* xs = xb + sg * 16 * 64 + cbase + c;
        const float* wq = W_query + sg * 16;
        #pragma unroll 4
        for (int i = 0; i < 16; ++i) {
            float v = xs[i * 64] - xo;
            a0 += wq[i] * v;        a1 += wq[512 + i] * v;
            a2 += wq[1024 + i] * v; a3 += wq[1536 + i] * v;
            a4 += wq[2048 + i] * v; a5 += wq[2560 + i] * v;
        }
        float* qp = (float*)uni;
        qp[(sg * 6 + 0) * 17 + c] = a0; qp[(sg * 6 + 1) * 17 + c] = a1;
        qp[(sg * 6 + 2) * 17 + c] = a2; qp[(sg * 6 + 3) * 17 + c] = a3;
        qp[(sg * 6 + 4) * 17 + c] = a4; qp[(sg * 6 + 5) * 17 + c] = a5;
    }
    __syncthreads();
    if (t < 96) {
        int w = t >> 4, c = t & 15;
        const float* qp = (const float*)uni;
        float s = 0;
        #pragma unroll 8
        for (int sg = 0; sg < 32; ++sg) s += qp[(sg * 6 + w) * 17 + c];
        qfin[w * 17 + c] = s;
    }
    __syncthreads();
    if (t < 16) {
        int c = t;
        float e[6];
        #pragma unroll
        for (int w = 0; w < 6; ++w) e[w] = cosf(qfin[w * 17 + c] + ws[WS_QBIAS + w]);
        int grow = (b * 64 + cbase + c) * 4;
        float best = -1e30f; int bm = 0;
        #pragma unroll
        for (int m = 0; m < 4; ++m) {
            float lg = b_prob[m];
            #pragma unroll
            for (int w = 0; w < 6; ++w) lg += W_prob[m * 6 + w] * e[w];
            lg += gumbel[grow + m];          // argmax invariant under /0.5 scale
            if (lg > best) { best = lg; bm = m; }
        }
        m_sel[c] = bm;
    }
    __syncthreads();

    // ---- gather selected retrieval rows -> selbuf (bf16, j padded to 128 with 0) ----
    {
        const int idxb = index[b];
        #pragma unroll
        for (int L = t; L < 2048; L += 512) {
            int c = L & 15, j = L >> 4;
            short v = 0;
            if (j < 104) {
                int i, row;
                if (j < 48)      { i = 0; row = j * 2; }
                else if (j < 80) { i = 1; row = (j - 48) * 3; }
                else             { i = 2; row = (j - 80) * 4; }
                v = f2bf(RT[(size_t)i * 122880000ull + (size_t)idxb * 24576ull
                            + (size_t)m_sel[c] * 6144ull + (size_t)row * 64ull + cbase + c]);
            }
            selbuf[c * 136 + j] = v;
        }
    }

    const int w = t >> 6;          // wave id
    const int lane = t & 63;
    char* Abuf = (char*)uni;
    const char* Apack = (const char*)ws;

    // hoist x-offset for stage waves
    const int Ls = t - 384;
    float xo0 = 0, xo1 = 0, xo2 = 0, xo3 = 0;
    if (t >= 384) {
        int c4 = (Ls & 3) * 4;
        xo0 = xoffs[c4 + 0]; xo1 = xoffs[c4 + 1]; xo2 = xoffs[c4 + 2]; xo3 = xoffs[c4 + 3];
    }

    f32x4 acc = {0.f, 0.f, 0.f, 0.f};

    for (int ch = 0; ch < 10; ++ch) {
        // (A) issue global loads (overlap with previous compute)
        float4 a0 = *(const float4*)(Apack + ch * 12288 + t * 16);
        float4 a1;
        if (t < 256) a1 = *(const float4*)(Apack + ch * 12288 + 8192 + t * 16);
        float4 x0, x1;
        if (ch < 8 && t >= 384) {
            int i0 = Ls, i1 = Ls + 128;
            x0 = *(const float4*)(xb + (ch * 64 + (i0 >> 2)) * 64 + cbase + (i0 & 3) * 4);
            x1 = *(const float4*)(xb + (ch * 64 + (i1 >> 2)) * 64 + cbase + (i1 & 3) * 4);
        }
        __syncthreads();   // previous compute finished reading LDS
        // (C) LDS writes
        *(float4*)(Abuf + t * 16) = a0;
        if (t < 256) *(float4*)(Abuf + 8192 + t * 16) = a1;
        if (ch < 8 && t >= 384) {
            int c4 = (Ls & 3) * 4;
            int sl0 = Ls >> 2, sl1 = (Ls + 128) >> 2;
            xbuf[(c4 + 0) * 72 + sl0] = f2bf(x0.x - xo0);
            xbuf[(c4 + 1) * 72 + sl0] = f2bf(x0.y - xo1);
            xbuf[(c4 + 2) * 72 + sl0] = f2bf(x0.z - xo2);
            xbuf[(c4 + 3) * 72 + sl0] = f2bf(x0.w - xo3);
            xbuf[(c4 + 0) * 72 + sl1] = f2bf(x1.x - xo0);
            xbuf[(c4 + 1) * 72 + sl1] = f2bf(x1.y - xo1);
            xbuf[(c4 + 2) * 72 + sl1] = f2bf(x1.z - xo2);
            xbuf[(c4 + 3) * 72 + sl1] = f2bf(x1.w - xo3);
        }
        __syncthreads();   // tile ready
        // (E) compute: waves 0..5, one 16x16 tile each, 2 MFMA k-steps of 32
        if (w < 6) {
            int g = lane >> 4, cl = lane & 15;
            if (ch < 8) {
                #pragma unroll
                for (int ks = 0; ks < 2; ++ks) {
                    bf16x8 av = *(const bf16x8*)(Abuf + (ks * 6 + w) * 1024 + lane * 16);
                    bf16x8 bv = *(const bf16x8*)(&xbuf[cl * 72 + ks * 32 + g * 8]);
                    acc = __builtin_amdgcn_mfma_f32_16x16x32_bf16(av, bv, acc, 0, 0, 0);
                }
            } else {
                int kbase = (ch - 8) * 64;
                #pragma unroll
                for (int ks = 0; ks < 2; ++ks) {
                    bf16x8 av = *(const bf16x8*)(Abuf + (ks * 6 + w) * 1024 + lane * 16);
                    bf16x8 bv = *(const bf16x8*)(&selbuf[cl * 136 + kbase + ks * 32 + g * 8]);
                    acc = __builtin_amdgcn_mfma_f32_16x16x32_bf16(av, bv, acc, 0, 0, 0);
                }
            }
        }
    }

    // ---- epilogue: D layout col=lane&15, row=4*(lane>>4)+reg (m89-verified) ----
    if (w < 6) {
        int g = lane >> 4, cl = lane & 15;
        float xo = xoffs[cl];
        int r0 = w * 16 + g * 4;
        const float* cst = ws + WS_CONST;
        float* op = out + (size_t)b * 6144 + (size_t)r0 * 64 + cbase + cl;
        op[0]       = acc[0] + cst[r0 + 0] + xo;
        op[64]      = acc[1] + cst[r0 + 1] + xo;
        op[128]     = acc[2] + cst[r0 + 2] + xo;
        op[192]     = acc[3] + cst[r0 + 3] + xo;
    }
}

extern "C" void kernel_launch(void* const* d_in, const int* in_sizes, int n_in,
                              void* d_out, int out_size, void* d_ws, size_t ws_size,
                              hipStream_t stream) {
    (void)in_sizes; (void)n_in; (void)out_size; (void)ws_size;
    const float* x_enc   = (const float*)d_in[0];
    const int*   index   = (const int*)d_in[1];
    const float* W_query = (const float*)d_in[2];
    const float* b_query = (const float*)d_in[3];
    const float* W_x     = (const float*)d_in[4];
    const float* b_x     = (const float*)d_in[5];
    const float* W_prob  = (const float*)d_in[6];
    const float* b_prob  = (const float*)d_in[7];
    const float* W_ret0  = (const float*)d_in[8];
    const float* b_ret0  = (const float*)d_in[9];
    const float* W_ret1  = (const float*)d_in[10];
    const float* b_ret1  = (const float*)d_in[11];
    const float* W_ret2  = (const float*)d_in[12];
    const float* b_ret2  = (const float*)d_in[13];
    const float* W_pred  = (const float*)d_in[14];
    const float* b_pred  = (const float*)d_in[15];
    const float* RT      = (const float*)d_in[16];
    const float* angles  = (const float*)d_in[17];
    const int*   wires   = (const int*)d_in[18];
    const float* gumbel  = (const float*)d_in[19];
    float* out = (float*)d_out;
    float* ws  = (float*)d_ws;

    prep_kernel<<<81, 256, 0, stream>>>(W_query, b_query, W_x, b_x,
                                        W_ret0, b_ret0, W_ret1, b_ret1, W_ret2, b_ret2,
                                        W_pred, b_pred, angles, wires, ws);
    main_kernel<<<512, 512, 0, stream>>>(x_enc, index, W_query, W_prob, b_prob,
                                         RT, gumbel, ws, out);
}

// Round 3
// 25.107 us; speedup vs baseline: 2.3282x; 1.1981x over previous
//
#include <hip/hip_runtime.h>

// ---------------- types / helpers ----------------
typedef short bf16x8 __attribute__((ext_vector_type(8)));
typedef float f32x4  __attribute__((ext_vector_type(4)));

// ws layout (floats): [0,30720) = Apack (61440 bf16 = 20 ksteps * 6144 B)
//                     [30720,30816) = cst96, [30816,30822) = qbias
#define WS_CONST 30720
#define WS_QBIAS 30816

__device__ __forceinline__ short f2bf(float f) {
    unsigned u = __float_as_uint(f);
    unsigned r = (u + 0x7FFFu + ((u >> 16) & 1u)) >> 16;  // RNE
    return (short)r;
}

// ---------------- prep: pack A = [M1 | M2] into MFMA fragment order (bf16) ----------------
// Apack layout: [kstep32 0..19][mt 0..5][lane 0..63][8 bf16]
//   elem e of lane holds M[mt*16+(lane&15)][kstep*32 + 8*(lane>>4) + e]
// ksteps 0..15: M1 = W_pred[:, :96] @ W_x  (k = s, 0..511)
// ksteps 16..19: M2 = W_pred[:, 96:] @ blockdiag(W_ret) cols (k = 512 + j, j 0..127, zero j>=104)
__global__ __launch_bounds__(256) void prep_kernel(
    const float* __restrict__ W_query, const float* __restrict__ b_query,
    const float* __restrict__ W_x,     const float* __restrict__ b_x,
    const float* __restrict__ W_ret0,  const float* __restrict__ b_ret0,
    const float* __restrict__ W_ret1,  const float* __restrict__ b_ret1,
    const float* __restrict__ W_ret2,  const float* __restrict__ b_ret2,
    const float* __restrict__ W_pred,  const float* __restrict__ b_pred,
    const float* __restrict__ angles,  const int* __restrict__ wires,
    float* __restrict__ ws)
{
    const int bid = blockIdx.x;
    const int t = threadIdx.x;
    __shared__ float wp[9216];   // W_pred half [96][96]
    __shared__ float wsl[768];   // slice [96][8]
    short* ap = (short*)ws;

    if (bid < 80) {
        const bool isM1 = bid < 64;
        for (int L = t; L < 9216; L += 256) {
            int r = L / 96, k = L - r * 96;
            wp[L] = W_pred[r * 192 + (isM1 ? k : 96 + k)];
        }
        if (isM1) {
            const int s0 = bid * 8;
            for (int L = t; L < 768; L += 256) {
                int k = L >> 3, s = L & 7;
                wsl[L] = W_x[k * 512 + s0 + s];
            }
        } else {
            const int j0 = (bid - 64) * 8;
            for (int L = t; L < 768; L += 256) {
                int k = L >> 3, jj = L & 7;
                int j = j0 + jj;
                float v = 0.f;
                if (j < 104) {
                    const float* Wr; int d, jl;
                    if (j < 48)      { Wr = W_ret0; d = 48; jl = j; }
                    else if (j < 80) { Wr = W_ret1; d = 32; jl = j - 48; }
                    else             { Wr = W_ret2; d = 24; jl = j - 80; }
                    v = Wr[k * d + jl];
                }
                wsl[L] = v;
            }
        }
        __syncthreads();
        #pragma unroll
        for (int i = 0; i < 3; ++i) {
            int idx = t + i * 256;             // 0..767
            int r = idx >> 3, s = idx & 7;
            float acc = 0.f;
            #pragma unroll 8
            for (int k = 0; k < 96; ++k) acc += wp[r * 96 + k] * wsl[k * 8 + s];
            int sg = isM1 ? (bid * 8 + s) : (512 + (bid - 64) * 8 + s);
            int kstep = sg >> 5, s32 = sg & 31;
            int g = s32 >> 3, e = s32 & 7;
            ap[kstep * 3072 + (r >> 4) * 512 + (g * 16 + (r & 15)) * 8 + e] = f2bf(acc);
        }
    } else {
        if (t < 96) {
            float v = b_pred[t];
            for (int k = 0; k < 96; ++k) {
                v += W_pred[t * 192 + k] * b_x[k];
                v += W_pred[t * 192 + 96 + k] * (b_ret0[k] + b_ret1[k] + b_ret2[k]);
            }
            ws[WS_CONST + t] = v;
        } else if (t < 102) {
            int w = t - 96;
            float v = b_query[w];
            for (int k = 0; k < 18; ++k)
                if (wires[k] == w) v += angles[k];
            ws[WS_QBIAS + w] = v;
        }
    }
}

// ---------------- main fused kernel ----------------
// grid 256 = (b 0..127) x (c-half 0..1, 32 cols); 512 threads = 8 waves.
// Single coalesced x pass produces fp32 q-partials AND the persistent bf16 xbuf.
// Then 6 compute waves run the K=640 MFMA GEMM (A streamed in 5 chunks of 128k).
__global__ __launch_bounds__(512) void main_kernel(
    const float* __restrict__ x_enc,
    const int*   __restrict__ index,
    const float* __restrict__ W_query,
    const float* __restrict__ W_prob,
    const float* __restrict__ b_prob,
    const float* __restrict__ RT,
    const float* __restrict__ gumbel,
    const float* __restrict__ ws,
    float* __restrict__ out)
{
    const int bid = blockIdx.x;
    const int b = bid >> 1;
    const int cbase = (bid & 1) * 32;
    const int t = threadIdx.x;
    const int lane = t & 63;
    const int wv = t >> 6;

    __shared__ __align__(16) union {
        struct { float wq[3072]; float qp[3072]; } s0;  // wq: W_query copy; qp: q partials [16][6][32]
        char Abuf[24576];                                // A chunk (128 k)
    } u0;
    __shared__ __align__(16) short xbuf[32][520];        // [c][k 512] bf16, stride 1040 B (16B-aligned)
    __shared__ __align__(16) union {
        float qfin[192];                                 // [w6][32]
        short selbuf[32][136];                           // [c][j 128+pad] bf16
    } u1;
    __shared__ int m_sel[32];

    const float* __restrict__ xb = x_enc + (size_t)b * 32768;

    // stage W_query into LDS (float4, coalesced)
    {
        const float4* wsrc = (const float4*)W_query;
        float4* wdst = (float4*)u0.s0.wq;
        for (int L = t; L < 768; L += 512) wdst[L] = wsrc[L];
    }

    // issue the single x pass: thread (c, sg) loads 32 rows at column c
    const int c  = t & 31;
    const int sg = t >> 5;
    const float xo = xb[511 * 64 + cbase + c];
    const float* xs = xb + (size_t)(sg * 32) * 64 + cbase + c;
    float v[32];
    #pragma unroll
    for (int i = 0; i < 32; ++i) v[i] = xs[i * 64];

    __syncthreads();   // wq visible

    // fp32 q partials + bf16 conversion + xbuf writes
    {
        #pragma unroll
        for (int i = 0; i < 32; ++i) v[i] -= xo;
        const float4* wq4 = (const float4*)u0.s0.wq;     // [6][128] float4 view
        float* qp = u0.s0.qp;
        #pragma unroll
        for (int wr = 0; wr < 6; ++wr) {
            float a = 0.f;
            #pragma unroll
            for (int i8 = 0; i8 < 8; ++i8) {
                float4 w4 = wq4[wr * 128 + sg * 8 + i8];  // uniform per half-wave -> broadcast
                a += w4.x * v[i8*4+0] + w4.y * v[i8*4+1] + w4.z * v[i8*4+2] + w4.w * v[i8*4+3];
            }
            qp[sg * 192 + wr * 32 + c] = a;
        }
        short* xrow = &xbuf[c][sg * 32];
        #pragma unroll
        for (int i = 0; i < 32; i += 2) {
            unsigned lo = (unsigned short)f2bf(v[i]);
            unsigned hi = (unsigned short)f2bf(v[i+1]);
            *(unsigned*)&xrow[i] = lo | (hi << 16);
        }
    }
    __syncthreads();

    // q reduce over sg
    if (t < 192) {
        int w6 = t >> 5, cc = t & 31;
        const float* qp = u0.s0.qp;
        float s = 0.f;
        #pragma unroll
        for (int g2 = 0; g2 < 16; ++g2) s += qp[g2 * 192 + w6 * 32 + cc];
        u1.qfin[w6 * 32 + cc] = s;
    }
    __syncthreads();

    // argmax (fp32 q path)
    if (t < 32) {
        float e[6];
        #pragma unroll
        for (int w = 0; w < 6; ++w) e[w] = cosf(u1.qfin[w * 32 + t] + ws[WS_QBIAS + w]);
        int grow = (b * 64 + cbase + t) * 4;
        float best = -1e30f; int bm = 0;
        #pragma unroll
        for (int m = 0; m < 4; ++m) {
            float lg = b_prob[m];
            #pragma unroll
            for (int w = 0; w < 6; ++w) lg += W_prob[m * 6 + w] * e[w];
            lg += gumbel[grow + m];          // argmax invariant under /0.5
            if (lg > best) { best = lg; bm = m; }   // first-max like jnp.argmax
        }
        m_sel[t] = bm;
    }
    __syncthreads();   // m_sel ready; qfin dead -> selbuf region reusable

    // gather selected retrieval rows -> selbuf (bf16, zero-padded j>=104)
    {
        const int idxb = index[b];
        for (int L = t; L < 32 * 136; L += 512) {
            int cc = L & 31, j = L >> 5;
            short val = 0;
            if (j < 104) {
                int i, row;
                if (j < 48)      { i = 0; row = j * 2; }
                else if (j < 80) { i = 1; row = (j - 48) * 3; }
                else             { i = 2; row = (j - 80) * 4; }
                val = f2bf(RT[(size_t)i * 122880000ull + (size_t)idxb * 24576ull
                             + (size_t)m_sel[cc] * 6144ull + (size_t)row * 64ull + cbase + cc]);
            }
            u1.selbuf[cc][j] = val;
        }
    }

    // MFMA loop: 5 chunks x 128 k; waves 0..5 each own 16 rows x 32 cols
    const char* Apack = (const char*)ws;
    const int cl = lane & 15, g = lane >> 4;
    f32x4 acc0 = {0,0,0,0}, acc1 = {0,0,0,0};
    for (int ch = 0; ch < 5; ++ch) {
        const float4* asrc = (const float4*)(Apack + ch * 24576);
        float4 r0 = asrc[t], r1 = asrc[t + 512], r2 = asrc[t + 1024];
        __syncthreads();   // prev chunk compute done (and, at ch=0, selbuf writes done)
        float4* adst = (float4*)u0.Abuf;
        adst[t] = r0; adst[t + 512] = r1; adst[t + 1024] = r2;
        __syncthreads();   // Abuf ready
        if (wv < 6) {
            #pragma unroll
            for (int ks = 0; ks < 4; ++ks) {
                bf16x8 av = *(const bf16x8*)(u0.Abuf + ks * 6144 + wv * 1024 + lane * 16);
                bf16x8 bv0, bv1;
                if (ch < 4) {
                    int kb = ch * 128 + ks * 32 + g * 8;
                    bv0 = *(const bf16x8*)&xbuf[cl][kb];
                    bv1 = *(const bf16x8*)&xbuf[16 + cl][kb];
                } else {
                    int kb = ks * 32 + g * 8;
                    bv0 = *(const bf16x8*)&u1.selbuf[cl][kb];
                    bv1 = *(const bf16x8*)&u1.selbuf[16 + cl][kb];
                }
                acc0 = __builtin_amdgcn_mfma_f32_16x16x32_bf16(av, bv0, acc0, 0, 0, 0);
                acc1 = __builtin_amdgcn_mfma_f32_16x16x32_bf16(av, bv1, acc1, 0, 0, 0);
            }
        }
    }

    // epilogue: D layout col=lane&15, row=4*(lane>>4)+reg (m89-verified, matches R2)
    if (wv < 6) {
        const float* cst = ws + WS_CONST;
        float xo0 = xb[511 * 64 + cbase + cl];
        float xo1 = xb[511 * 64 + cbase + 16 + cl];
        int r0 = wv * 16 + g * 4;
        float* op = out + (size_t)b * 6144 + (size_t)r0 * 64 + cbase;
        #pragma unroll
        for (int reg = 0; reg < 4; ++reg) {
            float cv = cst[r0 + reg];
            op[reg * 64 + cl]      = acc0[reg] + cv + xo0;
            op[reg * 64 + 16 + cl] = acc1[reg] + cv + xo1;
        }
    }
}

extern "C" void kernel_launch(void* const* d_in, const int* in_sizes, int n_in,
                              void* d_out, int out_size, void* d_ws, size_t ws_size,
                              hipStream_t stream) {
    (void)in_sizes; (void)n_in; (void)out_size; (void)ws_size;
    const float* x_enc   = (const float*)d_in[0];
    const int*   index   = (const int*)d_in[1];
    const float* W_query = (const float*)d_in[2];
    const float* b_query = (const float*)d_in[3];
    const float* W_x     = (const float*)d_in[4];
    const float* b_x     = (const float*)d_in[5];
    const float* W_prob  = (const float*)d_in[6];
    const float* b_prob  = (const float*)d_in[7];
    const float* W_ret0  = (const float*)d_in[8];
    const float* b_ret0  = (const float*)d_in[9];
    const float* W_ret1  = (const float*)d_in[10];
    const float* b_ret1  = (const float*)d_in[11];
    const float* W_ret2  = (const float*)d_in[12];
    const float* b_ret2  = (const float*)d_in[13];
    const float* W_pred  = (const float*)d_in[14];
    const float* b_pred  = (const float*)d_in[15];
    const float* RT      = (const float*)d_in[16];
    const float* angles  = (const float*)d_in[17];
    const int*   wires   = (const int*)d_in[18];
    const float* gumbel  = (const float*)d_in[19];
    float* out = (float*)d_out;
    float* ws  = (float*)d_ws;

    prep_kernel<<<81, 256, 0, stream>>>(W_query, b_query, W_x, b_x,
                                        W_ret0, b_ret0, W_ret1, b_ret1, W_ret2, b_ret2,
                                        W_pred, b_pred, angles, wires, ws);
    main_kernel<<<256, 512, 0, stream>>>(x_enc, index, W_query, W_prob, b_prob,
                                         RT, gumbel, ws, out);
}